// Round 1
// baseline (1762.206 us; speedup 1.0000x reference)
//
#include <hip/hip_runtime.h>
#include <math.h>

#define D 64
#define EPS 1e-12f
#define LN_EPS 1e-5f

// ---------------------------------------------------------------------------
// Kernel A: per-node linears.
// thread-per-node: all lanes process the same (d,k) each step -> weight loads
// are wave-uniform (scalar-pipe broadcast); h/p rows live in registers with
// statically-indexed unrolled loops.
// Outputs: sigmaQ = exp(tanh(qk)), sigmaK = exp(sigmoid(qk)), vh, B1h, B2h,
//          C1p, C2p  (all [N,64] fp32 in ws).
// ---------------------------------------------------------------------------
__global__ void __launch_bounds__(256)
node_linears(const float* __restrict__ h, const float* __restrict__ p,
             const float* __restrict__ WK, const float* __restrict__ bK,
             const float* __restrict__ WV, const float* __restrict__ bV,
             const float* __restrict__ WB1, const float* __restrict__ bB1,
             const float* __restrict__ WB2, const float* __restrict__ bB2,
             const float* __restrict__ WC1, const float* __restrict__ bC1,
             const float* __restrict__ WC2, const float* __restrict__ bC2,
             float* __restrict__ sigmaQ, float* __restrict__ sigmaK,
             float* __restrict__ vhArr, float* __restrict__ B1h,
             float* __restrict__ B2h, float* __restrict__ C1p,
             float* __restrict__ C2p, int N)
{
    int n = blockIdx.x * blockDim.x + threadIdx.x;
    if (n >= N) return;

    float hx[D], px[D];
    const float4* h4 = (const float4*)(h + (size_t)n * D);
    const float4* p4 = (const float4*)(p + (size_t)n * D);
#pragma unroll
    for (int j = 0; j < D / 4; ++j) {
        float4 a = h4[j];
        hx[4*j+0] = a.x; hx[4*j+1] = a.y; hx[4*j+2] = a.z; hx[4*j+3] = a.w;
        float4 b = p4[j];
        px[4*j+0] = b.x; px[4*j+1] = b.y; px[4*j+2] = b.z; px[4*j+3] = b.w;
    }

    for (int d = 0; d < D; ++d) {
        // qk and vh: [2D] input = concat(h,p)
        float aq = bK[d];
        float av = bV[d];
        const float4* wk4 = (const float4*)(WK + (size_t)d * 2 * D);
        const float4* wv4 = (const float4*)(WV + (size_t)d * 2 * D);
#pragma unroll
        for (int j = 0; j < D / 4; ++j) {
            float4 wq = wk4[j];
            aq += wq.x*hx[4*j] + wq.y*hx[4*j+1] + wq.z*hx[4*j+2] + wq.w*hx[4*j+3];
            float4 wv = wv4[j];
            av += wv.x*hx[4*j] + wv.y*hx[4*j+1] + wv.z*hx[4*j+2] + wv.w*hx[4*j+3];
        }
#pragma unroll
        for (int j = 0; j < D / 4; ++j) {
            float4 wq = wk4[D/4 + j];
            aq += wq.x*px[4*j] + wq.y*px[4*j+1] + wq.z*px[4*j+2] + wq.w*px[4*j+3];
            float4 wv = wv4[D/4 + j];
            av += wv.x*px[4*j] + wv.y*px[4*j+1] + wv.z*px[4*j+2] + wv.w*px[4*j+3];
        }
        float a1 = bB1[d], a2 = bB2[d], c1 = bC1[d], c2 = bC2[d];
        const float4* w1 = (const float4*)(WB1 + (size_t)d * D);
        const float4* w2 = (const float4*)(WB2 + (size_t)d * D);
        const float4* u1 = (const float4*)(WC1 + (size_t)d * D);
        const float4* u2 = (const float4*)(WC2 + (size_t)d * D);
#pragma unroll
        for (int j = 0; j < D / 4; ++j) {
            float4 q1 = w1[j];
            a1 += q1.x*hx[4*j] + q1.y*hx[4*j+1] + q1.z*hx[4*j+2] + q1.w*hx[4*j+3];
            float4 q2 = w2[j];
            a2 += q2.x*hx[4*j] + q2.y*hx[4*j+1] + q2.z*hx[4*j+2] + q2.w*hx[4*j+3];
            float4 r1 = u1[j];
            c1 += r1.x*px[4*j] + r1.y*px[4*j+1] + r1.z*px[4*j+2] + r1.w*px[4*j+3];
            float4 r2 = u2[j];
            c2 += r2.x*px[4*j] + r2.y*px[4*j+1] + r2.z*px[4*j+2] + r2.w*px[4*j+3];
        }
        size_t o = (size_t)n * D + d;
        float sq = expf(tanhf(aq));
        float sk = expf(1.f / (1.f + expf(-aq)));
        sigmaQ[o] = sq;
        sigmaK[o] = sk;
        vhArr[o]  = av;
        B1h[o] = a1;
        B2h[o] = a2;
        C1p[o] = c1;
        C2p[o] = c2;
    }
}

// ---------------------------------------------------------------------------
// Kernel B: the edge pass (the big one). wave-per-edge, lane = feature dim.
//  - WB3 row `lane` preloaded into VGPRs (amortized over ~200 edges/wave)
//  - e-row loads are wave-uniform (scalar broadcast)
//  - hat_eta = B1h[src]+B2h[dst]+B3e; e_out = relu(hat_eta)
//  - alpha = <sigmaQ[src], sigmaK[dst]> via shfl_xor butterfly
//  - atomics accumulate the numerators; the 1/(S_sig+eps) factors out
//    of both segment sums, applied in finalize.
// ---------------------------------------------------------------------------
__global__ void __launch_bounds__(256)
edge_kernel(const float* __restrict__ e, const int* __restrict__ src,
            const int* __restrict__ dst,
            const float* __restrict__ WB3, const float* __restrict__ bB3,
            const float* __restrict__ B1h, const float* __restrict__ B2h,
            const float* __restrict__ sigmaQ, const float* __restrict__ sigmaK,
            const float* __restrict__ vhArr, const float* __restrict__ C2p,
            float* __restrict__ e_out, float* __restrict__ S_sig,
            float* __restrict__ S_v, float* __restrict__ S_p, int E)
{
    const int lane = threadIdx.x & 63;
    const int wid = __builtin_amdgcn_readfirstlane((int)(threadIdx.x >> 6));
    const int wpb = blockDim.x >> 6;
    const int gw = blockIdx.x * wpb + wid;
    const int nw = gridDim.x * wpb;

    // WB3 row for this lane, in registers (16 float4 = 64 VGPR)
    float4 wb3[16];
    const float4* w4 = (const float4*)(WB3 + (size_t)lane * D);
#pragma unroll
    for (int j = 0; j < 16; ++j) wb3[j] = w4[j];
    const float bb3 = bB3[lane];

    for (int ed = gw; ed < E; ed += nw) {
        int s = src[ed];   // wave-uniform
        int t = dst[ed];   // wave-uniform
        const float4* er4 = (const float4*)(e + (size_t)ed * D);  // uniform base
        float b3 = bb3;
#pragma unroll
        for (int j = 0; j < 16; ++j) {
            float4 ev = er4[j];  // broadcast
            b3 += ev.x*wb3[j].x + ev.y*wb3[j].y + ev.z*wb3[j].z + ev.w*wb3[j].w;
        }
        size_t so = (size_t)s * D + lane;
        size_t to = (size_t)t * D + lane;
        float he = B1h[so] + B2h[to] + b3;
        e_out[(size_t)ed * D + lane] = fmaxf(he, 0.f);
        float sg = 1.f / (1.f + expf(-he));

        float prod = sigmaQ[so] * sigmaK[to];
#pragma unroll
        for (int off = 32; off > 0; off >>= 1) prod += __shfl_xor(prod, off);
        // prod == alpha (same on all lanes)

        unsafeAtomicAdd(&S_sig[to], sg);
        unsafeAtomicAdd(&S_v[to], sg * prod * vhArr[so]);
        unsafeAtomicAdd(&S_p[to], sg * C2p[so]);
    }
}

// ---------------------------------------------------------------------------
// Kernel C: node finalize. wave-per-node, lane = feature dim.
// h_out buffer arrives holding S_v, p_out holding S_p.
// ---------------------------------------------------------------------------
__global__ void __launch_bounds__(256)
finalize(const float* __restrict__ vhArr, const float* __restrict__ C1p,
         const float* __restrict__ S_sig, const float* __restrict__ ln_g,
         const float* __restrict__ ln_b, float* __restrict__ h_out,
         float* __restrict__ p_out, int N)
{
    const int lane = threadIdx.x & 63;
    const int wid = threadIdx.x >> 6;
    const int wpb = blockDim.x >> 6;
    for (int n = blockIdx.x * wpb + wid; n < N; n += gridDim.x * wpb) {
        size_t o = (size_t)n * D + lane;
        float denom = S_sig[o] + EPS;
        float hv = vhArr[o] + h_out[o] / denom;
        hv = fmaxf(hv, 0.f);
        // LayerNorm across the 64 lanes
        float s = hv;
#pragma unroll
        for (int off = 32; off > 0; off >>= 1) s += __shfl_xor(s, off);
        float mu = s * (1.f / 64.f);
        float dv = hv - mu;
        float s2 = dv * dv;
#pragma unroll
        for (int off = 32; off > 0; off >>= 1) s2 += __shfl_xor(s2, off);
        float var = s2 * (1.f / 64.f);
        h_out[o] = dv * rsqrtf(var + LN_EPS) * ln_g[lane] + ln_b[lane];

        float pv = C1p[o] + p_out[o] / denom;
        p_out[o] = tanhf(pv);
    }
}

extern "C" void kernel_launch(void* const* d_in, const int* in_sizes, int n_in,
                              void* d_out, int out_size, void* d_ws, size_t ws_size,
                              hipStream_t stream) {
    const float* h    = (const float*)d_in[0];
    const float* e    = (const float*)d_in[1];
    const float* p    = (const float*)d_in[2];
    const float* WK   = (const float*)d_in[3];
    const float* bK   = (const float*)d_in[4];
    const float* WV   = (const float*)d_in[5];
    const float* bV   = (const float*)d_in[6];
    const float* WB1  = (const float*)d_in[7];
    const float* bB1  = (const float*)d_in[8];
    const float* WB2  = (const float*)d_in[9];
    const float* bB2  = (const float*)d_in[10];
    const float* WB3  = (const float*)d_in[11];
    const float* bB3  = (const float*)d_in[12];
    const float* WC1  = (const float*)d_in[13];
    const float* bC1  = (const float*)d_in[14];
    const float* WC2  = (const float*)d_in[15];
    const float* bC2  = (const float*)d_in[16];
    const float* ln_g = (const float*)d_in[17];
    const float* ln_b = (const float*)d_in[18];
    const int*   src  = (const int*)d_in[19];
    const int*   dst  = (const int*)d_in[20];

    const int N = in_sizes[0] / D;
    const int E = in_sizes[1] / D;
    const size_t ND = (size_t)N * D;

    float* out   = (float*)d_out;
    float* h_out = out;                       // accumulates S_v, then h_out
    float* e_out = out + ND;
    float* p_out = out + ND + (size_t)E * D;  // accumulates S_p, then p_out

    float* ws     = (float*)d_ws;             // needs 8*N*64*4 = 102.4 MB
    float* sigmaQ = ws + 0 * ND;
    float* sigmaK = ws + 1 * ND;
    float* vhArr  = ws + 2 * ND;
    float* B1h    = ws + 3 * ND;
    float* B2h    = ws + 4 * ND;
    float* C1p    = ws + 5 * ND;
    float* C2p    = ws + 6 * ND;
    float* S_sig  = ws + 7 * ND;

    hipMemsetAsync(h_out, 0, ND * sizeof(float), stream);
    hipMemsetAsync(p_out, 0, ND * sizeof(float), stream);
    hipMemsetAsync(S_sig, 0, ND * sizeof(float), stream);

    node_linears<<<(N + 255) / 256, 256, 0, stream>>>(
        h, p, WK, bK, WV, bV, WB1, bB1, WB2, bB2, WC1, bC1, WC2, bC2,
        sigmaQ, sigmaK, vhArr, B1h, B2h, C1p, C2p, N);

    edge_kernel<<<1024, 256, 0, stream>>>(
        e, src, dst, WB3, bB3, B1h, B2h, sigmaQ, sigmaK, vhArr, C2p,
        e_out, S_sig, h_out, p_out, E);

    finalize<<<512, 256, 0, stream>>>(
        vhArr, C1p, S_sig, ln_g, ln_b, h_out, p_out, N);
}